// Round 15
// baseline (51.854 us; speedup 1.0000x reference)
//
#include <hip/hip_runtime.h>

// Problem constants: B=8, H=320, W=1024, CH=CW=3, MAXINS=200
#define BATCH   8
#define HW      (320 * 1024)        // 327680 pixels per batch
#define ELEMS   (HW * 9)            // 2949120 floats per batch
#define NF4     (ELEMS / 4)         // 737280 float4s per batch
#define MAXINS  200
#define BINS    (MAXINS * 9)        // 1800 bins; stride 9: gcd(9,32)=1 -> full
                                    // 32-bank spread
#define NXBLK   160                 // compress x-blocks per batch
#define F4PB    (NF4 / NXBLK)       // 4608 float4s per block
#define SCALE      2097152.0f       // 2^21 fixed-point scale
#define INV_SCALE_D (1.1 / 2097152.0)

// Decode an 8-element group starting at e (inflate path): spans <=2 pixels.
__device__ __forceinline__ void decode8(int e, int& pix0, int& pix1,
                                        int& j0, int& b) {
    pix0 = e / 9;
    j0   = e - pix0 * 9;
    b    = 9 - j0;
    pix1 = (e + 7) / 9;
}

// ---------------------------------------------------------------------------
// Compress, COALESCED form. R13/R14 ruled out TLP; R11 counters (9% VALU,
// 32% BW) + transaction arithmetic point at VMEM address processing: the
// quad layout's 144B lane stride made every float4 load 64 transactions/wave
// (vs 16 coalesced). Here thread t loads float4s base+t / base+t+256 ->
// lane-stride-1, 16 trans/wave-load. Pixel/j split is dynamic per float4
// (2 magic-divs + 2 L1-hit id loads + selects) - cheap at 9% VALUBusy.
// ---------------------------------------------------------------------------
__device__ __forceinline__ void accum_f4(
    const int* __restrict__ instb, const float4 v, const int g,
    int* __restrict__ bins)
{
    const int e    = g * 4;
    const int pix0 = e / 9;                  // magic-mul
    const int j0   = e - pix0 * 9;
    const int pix1 = (e + 3) / 9;            // == pix0 when j0 <= 5
    const int cnt  = 9 - j0;                 // elems in pix0 (>=4 when j0<=5)
    const int id0  = instb[pix0] * 9 + j0;
    const int id1  = instb[pix1] * 9 + j0 - 9;
    const float vv[4] = {v.x, v.y, v.z, v.w};
#pragma unroll
    for (int k = 0; k < 4; ++k) {
        const int base = (k < cnt) ? id0 : id1;
        atomicAdd(&bins[base + k], __float2int_rn(vv[k] * SCALE));
    }
}

__global__ __launch_bounds__(256) void epp_compress(
    const int* __restrict__ inst, const float* __restrict__ src,
    int* __restrict__ compi)
{
    __shared__ int bins[BINS];
    const int b = blockIdx.y;

    for (int i = threadIdx.x; i < BINS; i += 256) bins[i] = 0;
    __syncthreads();

    const int* __restrict__ instb = inst + b * HW;
    const float4* __restrict__ srcb = (const float4*)(src + (size_t)b * ELEMS);
    const int f0 = blockIdx.x * F4PB;

#pragma unroll
    for (int it = 0; it < F4PB / 512; ++it) {        // 9 iterations
        const int g1 = f0 + it * 512 + threadIdx.x;  // lane-stride-1
        const int g2 = g1 + 256;                     // lane-stride-1
        float4 v1 = srcb[g1];                        // both loads issue first
        float4 v2 = srcb[g2];
        accum_f4(instb, v1, g1, bins);
        accum_f4(instb, v2, g2, bins);
    }
    __syncthreads();

    // Identity flush: native global int atomics into the per-batch table.
    int* __restrict__ cb = compi + b * BINS;
    for (int i = threadIdx.x; i < BINS; i += 256) {
        atomicAdd(&cb[i], bins[i]);
    }
}

// ---------------------------------------------------------------------------
// Inflate (measured at its R+W roofline in R11: 16.5us/pass — unchanged):
// stage table in LDS converting int->float with 1.1/SCALE folded; decode8
// gather; coalesced float4 stores.
// ---------------------------------------------------------------------------
__global__ __launch_bounds__(256) void epp_inflate(
    const int* __restrict__ inst, const int* __restrict__ compi,
    float* __restrict__ out)
{
    __shared__ float bins[BINS];
    const int b = blockIdx.y;
    const int* __restrict__ cb = compi + b * BINS;
    for (int i = threadIdx.x; i < BINS; i += 256) {
        bins[i] = (float)((double)cb[i] * INV_SCALE_D);
    }
    __syncthreads();

    const int total8 = ELEMS / 8;
    const int* __restrict__ instb = inst + b * HW;
    float4* __restrict__ outb = (float4*)(out + (size_t)b * ELEMS);
    const int stride = gridDim.x * 256;

    for (int g = blockIdx.x * 256 + threadIdx.x; g < total8; g += stride) {
        const int e = g * 8;
        int pix0, pix1, j0, cnt8;
        decode8(e, pix0, pix1, j0, cnt8);
        const int id0 = instb[pix0] * 9 + j0;
        const int id1 = instb[pix1] * 9 + j0 - 9;
        float vals[8];
#pragma unroll
        for (int k = 0; k < 8; ++k) {
            int base = (k < cnt8) ? id0 : id1;
            vals[k] = bins[base + k];
        }
        outb[2 * g]     = make_float4(vals[0], vals[1], vals[2], vals[3]);
        outb[2 * g + 1] = make_float4(vals[4], vals[5], vals[6], vals[7]);
    }
}

extern "C" void kernel_launch(void* const* d_in, const int* in_sizes, int n_in,
                              void* d_out, int out_size, void* d_ws, size_t ws_size,
                              hipStream_t stream) {
    const int*   inst = (const int*)d_in[0];    // [B,1,H,W] int32
    const float* src  = (const float*)d_in[1];  // [B,H,W,3,3] f32
    float* out = (float*)d_out;                 // [B,H,W,3,3] f32

    const size_t compBytes = (size_t)BATCH * BINS * sizeof(int);   // 57.6 KB
    if (ws_size < compBytes) return;            // ws has always been >= 300MB

    int* compi = (int*)d_ws;

    // Zero the int accumulator every call (graph-safe, 57.6 KB).
    (void)hipMemsetAsync(compi, 0, compBytes, stream);

    dim3 cgrid(NXBLK, BATCH);                   // 1280 blocks, 256 threads
    epp_compress<<<cgrid, 256, 0, stream>>>(inst, src, compi);

    dim3 igrid(512, BATCH);                     // 4096 blocks (proven config)
    epp_inflate<<<igrid, 256, 0, stream>>>(inst, compi, out);
}

// Round 16
// 50.999 us; speedup vs baseline: 1.0168x; 1.0168x over previous
//
#include <hip/hip_runtime.h>

// Problem constants: B=8, H=320, W=1024, CH=CW=3, MAXINS=200
#define BATCH   8
#define HW      (320 * 1024)        // 327680 pixels per batch (mult of 4)
#define ELEMS   (HW * 9)            // 2949120 floats per batch
#define MAXINS  200
#define BINS    (MAXINS * 9)        // 1800 bins; stride 9: gcd(9,32)=1
#define NXBLK   160                 // compress x-blocks per batch
#define CBLK    512                 // 8 waves/block; 1280 blocks = 5/CU even
#define SCALE      2097152.0f       // 2^21 fixed-point scale
#define INV_SCALE_D (1.1 / 2097152.0)

// Decode an 8-element group starting at e (inflate path): spans <=2 pixels.
__device__ __forceinline__ void decode8(int e, int& pix0, int& pix1,
                                        int& j0, int& b) {
    pix0 = e / 9;
    j0   = e - pix0 * 9;
    b    = 9 - j0;
    pix1 = (e + 7) / 9;
}

// ---------------------------------------------------------------------------
// Compress, quad-pixel, 512-thread blocks, DUAL LDS HISTOGRAMS split by wave
// parity. Theory (last live mechanism): the single per-CU LDS atomic RMW
// unit serializes ~17 bank-cycles per wave ds_add (random 64->32 bank map x
// 3-4 cyc RMW bank occupancy) ~= 10us un-overlappable per CU; two copies
// halve per-bank collision pressure. Costs: +7.2KB LDS, 2-way merge flush.
// ---------------------------------------------------------------------------
__global__ __launch_bounds__(CBLK) void epp_compress(
    const int* __restrict__ inst, const float* __restrict__ src,
    int* __restrict__ compi)
{
    __shared__ int bins[2][BINS];
    const int b = blockIdx.y;

    for (int i = threadIdx.x; i < 2 * BINS; i += CBLK) bins[0][i] = 0;
    __syncthreads();

    const int* __restrict__ instb = inst + b * HW;
    const float4* __restrict__ srcb = (const float4*)(src + (size_t)b * ELEMS);

    // Wave-parity histogram selection: even waves -> copy 0, odd -> copy 1.
    int* __restrict__ mybins = bins[(threadIdx.x >> 6) & 1];

    const int q = blockIdx.x * CBLK + threadIdx.x;   // pixel-quad index
    const int p = q * 4;                             // first pixel (4-aligned)
    const int4 ids = *(const int4*)(instb + p);      // 16B-aligned id load
    int base[4] = {ids.x * 9, ids.y * 9, ids.z * 9, ids.w * 9};

    const float4* s = srcb + (size_t)q * 9;          // 36 floats
    float4 f[9];
#pragma unroll
    for (int r = 0; r < 9; ++r) f[r] = s[r];

#pragma unroll
    for (int r = 0; r < 9; ++r) {
        const float v[4] = {f[r].x, f[r].y, f[r].z, f[r].w};
#pragma unroll
        for (int c = 0; c < 4; ++c) {
            const int i  = 4 * r + c;                // 0..35, static
            const int px = i / 9;                    // static
            const int j  = i - px * 9;               // static
            atomicAdd(&mybins[base[px] + j],         // ds_add, imm offset j
                      __float2int_rn(v[c] * SCALE));
        }
    }
    __syncthreads();

    // Merge the two copies and flush via native global int atomics.
    int* __restrict__ cb = compi + b * BINS;
    for (int i = threadIdx.x; i < BINS; i += CBLK) {
        atomicAdd(&cb[i], bins[0][i] + bins[1][i]);
    }
}

// ---------------------------------------------------------------------------
// Inflate (measured ~85-90% of write ceiling in R11 — frozen): stage table
// in LDS converting int->float with 1.1/SCALE folded; decode8 gather;
// coalesced float4 stores.
// ---------------------------------------------------------------------------
__global__ __launch_bounds__(256) void epp_inflate(
    const int* __restrict__ inst, const int* __restrict__ compi,
    float* __restrict__ out)
{
    __shared__ float bins[BINS];
    const int b = blockIdx.y;
    const int* __restrict__ cb = compi + b * BINS;
    for (int i = threadIdx.x; i < BINS; i += 256) {
        bins[i] = (float)((double)cb[i] * INV_SCALE_D);
    }
    __syncthreads();

    const int total8 = ELEMS / 8;
    const int* __restrict__ instb = inst + b * HW;
    float4* __restrict__ outb = (float4*)(out + (size_t)b * ELEMS);
    const int stride = gridDim.x * 256;

    for (int g = blockIdx.x * 256 + threadIdx.x; g < total8; g += stride) {
        const int e = g * 8;
        int pix0, pix1, j0, cnt8;
        decode8(e, pix0, pix1, j0, cnt8);
        const int id0 = instb[pix0] * 9 + j0;
        const int id1 = instb[pix1] * 9 + j0 - 9;
        float vals[8];
#pragma unroll
        for (int k = 0; k < 8; ++k) {
            int base = (k < cnt8) ? id0 : id1;
            vals[k] = bins[base + k];
        }
        outb[2 * g]     = make_float4(vals[0], vals[1], vals[2], vals[3]);
        outb[2 * g + 1] = make_float4(vals[4], vals[5], vals[6], vals[7]);
    }
}

extern "C" void kernel_launch(void* const* d_in, const int* in_sizes, int n_in,
                              void* d_out, int out_size, void* d_ws, size_t ws_size,
                              hipStream_t stream) {
    const int*   inst = (const int*)d_in[0];    // [B,1,H,W] int32
    const float* src  = (const float*)d_in[1];  // [B,H,W,3,3] f32
    float* out = (float*)d_out;                 // [B,H,W,3,3] f32

    const size_t compBytes = (size_t)BATCH * BINS * sizeof(int);   // 57.6 KB
    if (ws_size < compBytes) return;            // ws has always been >= 300MB

    int* compi = (int*)d_ws;

    // Zero the int accumulator every call (graph-safe, 57.6 KB).
    (void)hipMemsetAsync(compi, 0, compBytes, stream);

    dim3 cgrid(NXBLK, BATCH);                   // 1280 blocks x 512 threads
    epp_compress<<<cgrid, CBLK, 0, stream>>>(inst, src, compi);

    dim3 igrid(512, BATCH);                     // 4096 blocks (proven config)
    epp_inflate<<<igrid, 256, 0, stream>>>(inst, compi, out);
}

// Round 17
// 50.986 us; speedup vs baseline: 1.0170x; 1.0002x over previous
//
#include <hip/hip_runtime.h>

// Problem constants: B=8, H=320, W=1024, CH=CW=3, MAXINS=200
#define BATCH   8
#define HW      (320 * 1024)        // 327680 pixels per batch (mult of 4)
#define ELEMS   (HW * 9)            // 2949120 floats per batch
#define MAXINS  200
#define BINS    (MAXINS * 9)        // 1800 bins; stride 9: gcd(9,32)=1 -> full
                                    // 32-bank spread
#define NXBLK   160                 // compress x-blocks per batch
#define CBLK    512                 // 8 waves/block, 1280 blocks = 5/CU even;
                                    // best-known config (R14, 50.5us)
#define SCALE      2097152.0f       // 2^21 fixed-point scale
#define INV_SCALE_D (1.1 / 2097152.0)

// Decode an 8-element group starting at e (inflate path): spans <=2 pixels.
__device__ __forceinline__ void decode8(int e, int& pix0, int& pix1,
                                        int& j0, int& b) {
    pix0 = e / 9;
    j0   = e - pix0 * 9;
    b    = 9 - j0;
    pix1 = (e + 7) / 9;
}

// ---------------------------------------------------------------------------
// Compress (R14 config — best known). Quad-pixel static decomposition:
// 1 int4 id load + 9 float4 loads per thread, 36 ds_add with static imm
// offsets, stride-9 LDS histogram, native global int-atomic flush.
// Exhausted-null mechanisms (do not revisit): more blocks (R13 +11us via
// flush fixed cost), more waves (R14 null), coalesced loads (R15 null),
// dual histograms (R16 null), stride-12 LDS (R10, 8-bank conflict).
// ---------------------------------------------------------------------------
__global__ __launch_bounds__(CBLK) void epp_compress(
    const int* __restrict__ inst, const float* __restrict__ src,
    int* __restrict__ compi)
{
    __shared__ int bins[BINS];
    const int b = blockIdx.y;

    for (int i = threadIdx.x; i < BINS; i += CBLK) bins[i] = 0;
    __syncthreads();

    const int* __restrict__ instb = inst + b * HW;
    const float4* __restrict__ srcb = (const float4*)(src + (size_t)b * ELEMS);

    const int q = blockIdx.x * CBLK + threadIdx.x;   // pixel-quad index
    const int p = q * 4;                             // first pixel (4-aligned)
    const int4 ids = *(const int4*)(instb + p);      // 16B-aligned id load
    int base[4] = {ids.x * 9, ids.y * 9, ids.z * 9, ids.w * 9};

    const float4* s = srcb + (size_t)q * 9;          // 36 floats, 16B-aligned
    float4 f[9];
#pragma unroll
    for (int r = 0; r < 9; ++r) f[r] = s[r];

#pragma unroll
    for (int r = 0; r < 9; ++r) {
        const float v[4] = {f[r].x, f[r].y, f[r].z, f[r].w};
#pragma unroll
        for (int c = 0; c < 4; ++c) {
            const int i  = 4 * r + c;                // 0..35, static
            const int px = i / 9;                    // static
            const int j  = i - px * 9;               // static
            atomicAdd(&bins[base[px] + j],           // ds_add, imm offset j
                      __float2int_rn(v[c] * SCALE));
        }
    }
    __syncthreads();

    // Identity flush: native global int atomics into the per-batch table.
    int* __restrict__ cb = compi + b * BINS;
    for (int i = threadIdx.x; i < BINS; i += CBLK) {
        atomicAdd(&cb[i], bins[i]);
    }
}

// ---------------------------------------------------------------------------
// Inflate (measured ~91% of the achieved write ceiling — frozen): stage
// table in LDS converting int->float with 1.1/SCALE folded; decode8 gather;
// coalesced float4 stores.
// ---------------------------------------------------------------------------
__global__ __launch_bounds__(256) void epp_inflate(
    const int* __restrict__ inst, const int* __restrict__ compi,
    float* __restrict__ out)
{
    __shared__ float bins[BINS];
    const int b = blockIdx.y;
    const int* __restrict__ cb = compi + b * BINS;
    for (int i = threadIdx.x; i < BINS; i += 256) {
        bins[i] = (float)((double)cb[i] * INV_SCALE_D);
    }
    __syncthreads();

    const int total8 = ELEMS / 8;
    const int* __restrict__ instb = inst + b * HW;
    float4* __restrict__ outb = (float4*)(out + (size_t)b * ELEMS);
    const int stride = gridDim.x * 256;

    for (int g = blockIdx.x * 256 + threadIdx.x; g < total8; g += stride) {
        const int e = g * 8;
        int pix0, pix1, j0, cnt8;
        decode8(e, pix0, pix1, j0, cnt8);
        const int id0 = instb[pix0] * 9 + j0;
        const int id1 = instb[pix1] * 9 + j0 - 9;
        float vals[8];
#pragma unroll
        for (int k = 0; k < 8; ++k) {
            int base = (k < cnt8) ? id0 : id1;
            vals[k] = bins[base + k];
        }
        outb[2 * g]     = make_float4(vals[0], vals[1], vals[2], vals[3]);
        outb[2 * g + 1] = make_float4(vals[4], vals[5], vals[6], vals[7]);
    }
}

extern "C" void kernel_launch(void* const* d_in, const int* in_sizes, int n_in,
                              void* d_out, int out_size, void* d_ws, size_t ws_size,
                              hipStream_t stream) {
    const int*   inst = (const int*)d_in[0];    // [B,1,H,W] int32
    const float* src  = (const float*)d_in[1];  // [B,H,W,3,3] f32
    float* out = (float*)d_out;                 // [B,H,W,3,3] f32

    const size_t compBytes = (size_t)BATCH * BINS * sizeof(int);   // 57.6 KB
    if (ws_size < compBytes) return;            // ws has always been >= 300MB

    int* compi = (int*)d_ws;

    // Zero the int accumulator every call (graph-safe, 57.6 KB).
    (void)hipMemsetAsync(compi, 0, compBytes, stream);

    dim3 cgrid(NXBLK, BATCH);                   // 1280 blocks x 512 threads
    epp_compress<<<cgrid, CBLK, 0, stream>>>(inst, src, compi);

    dim3 igrid(512, BATCH);                     // 4096 blocks (proven config)
    epp_inflate<<<igrid, 256, 0, stream>>>(inst, compi, out);
}

// Round 19
// 48.308 us; speedup vs baseline: 1.0734x; 1.0554x over previous
//
#include <hip/hip_runtime.h>

// Problem constants: B=8, H=320, W=1024, CH=CW=3, MAXINS=200
#define BATCH   8
#define HW      (320 * 1024)        // 327680 pixels per batch (mult of 4)
#define ELEMS   (HW * 9)            // 2949120 floats per batch
#define NQUADS  (HW / 4)            // 81920 pixel-quads per batch  <-- the
                                    // R18 crash: grid was sized to 327680
                                    // (pixel count), reading 4x OOB
#define MAXINS  200
#define BINS    (MAXINS * 9)        // 1800 bins; stride 9: gcd(9,32)=1
#define NXBLK   80                  // compress x-blocks per batch
#define CBLK    512                 // 8 waves/block
#define QPT     2                   // quads/thread: 80*512*2 = 81920 = NQUADS
#define SCALE      2097152.0f       // 2^21 fixed-point scale
#define INV_SCALE_D (1.1 / 2097152.0)

// Decode an 8-element group starting at e (inflate path): spans <=2 pixels.
__device__ __forceinline__ void decode8(int e, int& pix0, int& pix1,
                                        int& j0, int& b) {
    pix0 = e / 9;
    j0   = e - pix0 * 9;
    b    = 9 - j0;
    pix1 = (e + 7) / 9;
}

// ---------------------------------------------------------------------------
// Compress: R14 shape with HALF the histogram instances (640 vs 1280).
// Tests the one surviving mechanism: per-instance fixed cost (R13 measured
// +1280 instances = +11us via flush chains + LDS zeroing + churn). 640
// blocks are all co-resident (2-3/CU, 16-24 waves/CU; R14 proved wave-TLP
// is not the binder at 20-32 waves). Exhausted-null (do not revisit):
// more blocks (R13), more waves (R14), coalesced loads (R15), dual
// histograms (R16), stride-12 LDS (R10).
// ---------------------------------------------------------------------------
__global__ __launch_bounds__(CBLK) void epp_compress(
    const int* __restrict__ inst, const float* __restrict__ src,
    int* __restrict__ compi)
{
    __shared__ int bins[BINS];
    const int b = blockIdx.y;

    for (int i = threadIdx.x; i < BINS; i += CBLK) bins[i] = 0;
    __syncthreads();

    const int* __restrict__ instb = inst + b * HW;
    const float4* __restrict__ srcb = (const float4*)(src + (size_t)b * ELEMS);
    const int qbase = blockIdx.x * (CBLK * QPT) + threadIdx.x;

#pragma unroll 1
    for (int it = 0; it < QPT; ++it) {
        const int q = qbase + it * CBLK;             // max 81919 < NQUADS
        const int p = q * 4;                         // first pixel (4-aligned)
        const int4 ids = *(const int4*)(instb + p);  // 16B-aligned id load
        int base[4] = {ids.x * 9, ids.y * 9, ids.z * 9, ids.w * 9};

        const float4* s = srcb + (size_t)q * 9;      // 36 floats, 16B-aligned
        float4 f[9];
#pragma unroll
        for (int r = 0; r < 9; ++r) f[r] = s[r];

#pragma unroll
        for (int r = 0; r < 9; ++r) {
            const float v[4] = {f[r].x, f[r].y, f[r].z, f[r].w};
#pragma unroll
            for (int c = 0; c < 4; ++c) {
                const int i  = 4 * r + c;            // 0..35, static
                const int px = i / 9;                // static
                const int j  = i - px * 9;           // static
                atomicAdd(&bins[base[px] + j],       // ds_add, imm offset j
                          __float2int_rn(v[c] * SCALE));
            }
        }
    }
    __syncthreads();

    // Identity flush: native global int atomics into the per-batch table.
    int* __restrict__ cb = compi + b * BINS;
    for (int i = threadIdx.x; i < BINS; i += CBLK) {
        atomicAdd(&cb[i], bins[i]);
    }
}

// ---------------------------------------------------------------------------
// Inflate (measured ~81-91% of the achieved write ceiling — frozen): stage
// table in LDS converting int->float with 1.1/SCALE folded; decode8 gather;
// coalesced float4 stores.
// ---------------------------------------------------------------------------
__global__ __launch_bounds__(256) void epp_inflate(
    const int* __restrict__ inst, const int* __restrict__ compi,
    float* __restrict__ out)
{
    __shared__ float bins[BINS];
    const int b = blockIdx.y;
    const int* __restrict__ cb = compi + b * BINS;
    for (int i = threadIdx.x; i < BINS; i += 256) {
        bins[i] = (float)((double)cb[i] * INV_SCALE_D);
    }
    __syncthreads();

    const int total8 = ELEMS / 8;
    const int* __restrict__ instb = inst + b * HW;
    float4* __restrict__ outb = (float4*)(out + (size_t)b * ELEMS);
    const int stride = gridDim.x * 256;

    for (int g = blockIdx.x * 256 + threadIdx.x; g < total8; g += stride) {
        const int e = g * 8;
        int pix0, pix1, j0, cnt8;
        decode8(e, pix0, pix1, j0, cnt8);
        const int id0 = instb[pix0] * 9 + j0;
        const int id1 = instb[pix1] * 9 + j0 - 9;
        float vals[8];
#pragma unroll
        for (int k = 0; k < 8; ++k) {
            int base = (k < cnt8) ? id0 : id1;
            vals[k] = bins[base + k];
        }
        outb[2 * g]     = make_float4(vals[0], vals[1], vals[2], vals[3]);
        outb[2 * g + 1] = make_float4(vals[4], vals[5], vals[6], vals[7]);
    }
}

extern "C" void kernel_launch(void* const* d_in, const int* in_sizes, int n_in,
                              void* d_out, int out_size, void* d_ws, size_t ws_size,
                              hipStream_t stream) {
    const int*   inst = (const int*)d_in[0];    // [B,1,H,W] int32
    const float* src  = (const float*)d_in[1];  // [B,H,W,3,3] f32
    float* out = (float*)d_out;                 // [B,H,W,3,3] f32

    const size_t compBytes = (size_t)BATCH * BINS * sizeof(int);   // 57.6 KB
    if (ws_size < compBytes) return;            // ws has always been >= 300MB

    int* compi = (int*)d_ws;

    // Zero the int accumulator every call (graph-safe, 57.6 KB).
    (void)hipMemsetAsync(compi, 0, compBytes, stream);

    dim3 cgrid(NXBLK, BATCH);                   // 640 blocks x 512 threads
    epp_compress<<<cgrid, CBLK, 0, stream>>>(inst, src, compi);

    dim3 igrid(512, BATCH);                     // 4096 blocks (proven config)
    epp_inflate<<<igrid, 256, 0, stream>>>(inst, compi, out);
}

// Round 20
// 46.405 us; speedup vs baseline: 1.1174x; 1.0410x over previous
//
#include <hip/hip_runtime.h>

// Problem constants: B=8, H=320, W=1024, CH=CW=3, MAXINS=200
#define BATCH   8
#define HW      (320 * 1024)        // 327680 pixels per batch (mult of 4)
#define ELEMS   (HW * 9)            // 2949120 floats per batch
#define NQUADS  (HW / 4)            // 81920 pixel-quads per batch
#define MAXINS  200
#define BINS    (MAXINS * 9)        // 1800 bins; stride 9: gcd(9,32)=1
#define NXBLK   32                  // compress x-blocks per batch
#define CBLK    512                 // 8 waves/block
#define QPT     5                   // quads/thread: 32*512*5 = 81920 = NQUADS
#define SCALE      2097152.0f       // 2^21 fixed-point scale
#define INV_SCALE_D (1.1 / 2097152.0)

// Decode an 8-element group starting at e (inflate path): spans <=2 pixels.
__device__ __forceinline__ void decode8(int e, int& pix0, int& pix1,
                                        int& j0, int& b) {
    pix0 = e / 9;
    j0   = e - pix0 * 9;
    b    = 9 - j0;
    pix1 = (e + 7) / 9;
}

// ---------------------------------------------------------------------------
// Compress: 256 histogram instances (1 block/CU exactly, vs R19's 640).
// The instance-count slope is the only confirmed mechanism since R12:
// R13 (+1280 inst) = +11us, R19 (-640 inst) = -2.7us. This step: -384
// more instances -> flush atomics 1.15M -> 460K, LDS zeroing / 2.5.
// Occupancy falls to 8 waves/CU (untested; latency so far hidden by the
// 9-wide float4 ILP per iteration, not wave count). Exhausted-null:
// more blocks (R13), more waves (R14), coalesced loads (R15), dual
// histograms (R16), stride-12 LDS (R10).
// ---------------------------------------------------------------------------
__global__ __launch_bounds__(CBLK) void epp_compress(
    const int* __restrict__ inst, const float* __restrict__ src,
    int* __restrict__ compi)
{
    __shared__ int bins[BINS];
    const int b = blockIdx.y;

    for (int i = threadIdx.x; i < BINS; i += CBLK) bins[i] = 0;
    __syncthreads();

    const int* __restrict__ instb = inst + b * HW;
    const float4* __restrict__ srcb = (const float4*)(src + (size_t)b * ELEMS);
    const int qbase = blockIdx.x * (CBLK * QPT) + threadIdx.x;

#pragma unroll 1
    for (int it = 0; it < QPT; ++it) {
        const int q = qbase + it * CBLK;             // max 81919 < NQUADS
        const int p = q * 4;                         // first pixel (4-aligned)
        const int4 ids = *(const int4*)(instb + p);  // 16B-aligned id load
        int base[4] = {ids.x * 9, ids.y * 9, ids.z * 9, ids.w * 9};

        const float4* s = srcb + (size_t)q * 9;      // 36 floats, 16B-aligned
        float4 f[9];
#pragma unroll
        for (int r = 0; r < 9; ++r) f[r] = s[r];

#pragma unroll
        for (int r = 0; r < 9; ++r) {
            const float v[4] = {f[r].x, f[r].y, f[r].z, f[r].w};
#pragma unroll
            for (int c = 0; c < 4; ++c) {
                const int i  = 4 * r + c;            // 0..35, static
                const int px = i / 9;                // static
                const int j  = i - px * 9;           // static
                atomicAdd(&bins[base[px] + j],       // ds_add, imm offset j
                          __float2int_rn(v[c] * SCALE));
            }
        }
    }
    __syncthreads();

    // Identity flush: native global int atomics into the per-batch table.
    int* __restrict__ cb = compi + b * BINS;
    for (int i = threadIdx.x; i < BINS; i += CBLK) {
        atomicAdd(&cb[i], bins[i]);
    }
}

// ---------------------------------------------------------------------------
// Inflate (measured ~81-91% of the achieved write ceiling — frozen): stage
// table in LDS converting int->float with 1.1/SCALE folded; decode8 gather;
// coalesced float4 stores.
// ---------------------------------------------------------------------------
__global__ __launch_bounds__(256) void epp_inflate(
    const int* __restrict__ inst, const int* __restrict__ compi,
    float* __restrict__ out)
{
    __shared__ float bins[BINS];
    const int b = blockIdx.y;
    const int* __restrict__ cb = compi + b * BINS;
    for (int i = threadIdx.x; i < BINS; i += 256) {
        bins[i] = (float)((double)cb[i] * INV_SCALE_D);
    }
    __syncthreads();

    const int total8 = ELEMS / 8;
    const int* __restrict__ instb = inst + b * HW;
    float4* __restrict__ outb = (float4*)(out + (size_t)b * ELEMS);
    const int stride = gridDim.x * 256;

    for (int g = blockIdx.x * 256 + threadIdx.x; g < total8; g += stride) {
        const int e = g * 8;
        int pix0, pix1, j0, cnt8;
        decode8(e, pix0, pix1, j0, cnt8);
        const int id0 = instb[pix0] * 9 + j0;
        const int id1 = instb[pix1] * 9 + j0 - 9;
        float vals[8];
#pragma unroll
        for (int k = 0; k < 8; ++k) {
            int base = (k < cnt8) ? id0 : id1;
            vals[k] = bins[base + k];
        }
        outb[2 * g]     = make_float4(vals[0], vals[1], vals[2], vals[3]);
        outb[2 * g + 1] = make_float4(vals[4], vals[5], vals[6], vals[7]);
    }
}

extern "C" void kernel_launch(void* const* d_in, const int* in_sizes, int n_in,
                              void* d_out, int out_size, void* d_ws, size_t ws_size,
                              hipStream_t stream) {
    const int*   inst = (const int*)d_in[0];    // [B,1,H,W] int32
    const float* src  = (const float*)d_in[1];  // [B,H,W,3,3] f32
    float* out = (float*)d_out;                 // [B,H,W,3,3] f32

    const size_t compBytes = (size_t)BATCH * BINS * sizeof(int);   // 57.6 KB
    if (ws_size < compBytes) return;            // ws has always been >= 300MB

    int* compi = (int*)d_ws;

    // Zero the int accumulator every call (graph-safe, 57.6 KB).
    (void)hipMemsetAsync(compi, 0, compBytes, stream);

    dim3 cgrid(NXBLK, BATCH);                   // 256 blocks x 512 threads
    epp_compress<<<cgrid, CBLK, 0, stream>>>(inst, src, compi);

    dim3 igrid(512, BATCH);                     // 4096 blocks (proven config)
    epp_inflate<<<igrid, 256, 0, stream>>>(inst, compi, out);
}